// Round 2
// baseline (1504.221 us; speedup 1.0000x reference)
//
#include <hip/hip_runtime.h>
#include <stdint.h>
#include <stddef.h>

// ---------------------------------------------------------------------------
// MMRecBlock on MI355X. Harness buffers are fp32 (reference dtype). We convert
// weights/activations to bf16 in workspace for MFMA GEMMs, accumulate fp32,
// keep gamma / x_residual / outputs fp32. Workspace: ~296 MB.
// ---------------------------------------------------------------------------

#define DEV __device__ __forceinline__

typedef __attribute__((ext_vector_type(8))) short bh8;     // 8 x bf16
typedef __attribute__((ext_vector_type(4))) float f32x4;   // MFMA acc

typedef __attribute__((address_space(1))) uint32_t gu32;
typedef __attribute__((address_space(3))) uint32_t lu32;

DEV void async16(const void* g, void* l) {
  __builtin_amdgcn_global_load_lds((gu32*)g, (lu32*)l, 16, 0, 0);
}

DEV float b2f(short s) {
  union { float f; uint32_t u; } x;
  x.u = ((uint32_t)(uint16_t)s) << 16;
  return x.f;
}
DEV short f2b(float f) {  // RNE
  uint32_t u = __float_as_uint(f);
  u += 0x7fffu + ((u >> 16) & 1u);
  return (short)(u >> 16);
}
DEV float sigmoid_f(float x) { return 1.f / (1.f + __expf(-x)); }
DEV float gelu_f(float x) {   // tanh approximation (jax.nn.gelu default)
  float y = 0.7978845608028654f * (x + 0.044715f * x * x * x);
  float t = 1.f - 2.f / (__expf(2.f * y) + 1.f);
  return 0.5f * x * (1.f + t);
}

// ---------------------------------------------------------------------------
// GEMM: C[M,N] = A[M,K] @ B[K,N] (+bias fp32, epilogue). A row-major bf16,
// Bt = B^T row-major [N][K] bf16. 128x128 tile, BK=32, 256 thr = 4 waves,
// each wave 64x64 via 4x4 of mfma_f32_16x16x32_bf16. global_load_lds x16.
// EPI: 0 = bf16(acc+bias)            1 = bf16(gelu(acc+bias))
//      2 = f32(acc+bias)             3 = f32(sigmoid(acc+bias+f32 aux0))
//      4 = f32(acc+bias+f32 aux0+bf16 aux1)    5 = f32(acc+bias+f32 aux0)
// ---------------------------------------------------------------------------
template <int EPI>
__global__ __launch_bounds__(256) void gemm_k(
    const short* __restrict__ A, const short* __restrict__ Bt,
    const float* __restrict__ bias, void* Cv,
    const void* aux0, const void* aux1, int M, int N, int K) {
  __shared__ __align__(16) short sA[128 * 32];
  __shared__ __align__(16) short sB[128 * 32];
  const int tid  = threadIdx.x;
  const int lane = tid & 63;
  const int wave = tid >> 6;
  const int q = lane >> 4;   // 0..3
  const int r = lane & 15;   // 0..15
  const int m0 = blockIdx.y * 128;
  const int n0 = blockIdx.x * 128;
  const int wm = (wave >> 1) * 64;
  const int wn = (wave & 1) * 64;

  // staging chunks: L in [0,512), chunk = 8 bf16; row = L>>2, koff = (L&3)*8
  const int L0 = tid, L1 = 256 + tid;
  const short* gA0 = A + (size_t)(m0 + (L0 >> 2)) * K + (L0 & 3) * 8;
  const short* gA1 = A + (size_t)(m0 + (L1 >> 2)) * K + (L1 & 3) * 8;
  const short* gB0 = Bt + (size_t)(n0 + (L0 >> 2)) * K + (L0 & 3) * 8;
  const short* gB1 = Bt + (size_t)(n0 + (L1 >> 2)) * K + (L1 & 3) * 8;
  short* lA0 = &sA[L0 * 8];
  short* lA1 = &sA[L1 * 8];
  short* lB0 = &sB[L0 * 8];
  short* lB1 = &sB[L1 * 8];

  f32x4 acc[4][4] = {};
  const int nk = K >> 5;
  for (int kt = 0; kt < nk; ++kt) {
    __syncthreads();
    const int kb = kt << 5;
    async16(gA0 + kb, lA0);
    async16(gA1 + kb, lA1);
    async16(gB0 + kb, lB0);
    async16(gB1 + kb, lB1);
    asm volatile("s_waitcnt vmcnt(0)" ::: "memory");
    __syncthreads();
    bh8 af[4], bf[4];
#pragma unroll
    for (int i = 0; i < 4; ++i)
      af[i] = *(const bh8*)&sA[(wm + i * 16 + r) * 32 + q * 8];
#pragma unroll
    for (int j = 0; j < 4; ++j)
      bf[j] = *(const bh8*)&sB[(wn + j * 16 + r) * 32 + q * 8];
#pragma unroll
    for (int i = 0; i < 4; ++i)
#pragma unroll
      for (int j = 0; j < 4; ++j)
        acc[i][j] = __builtin_amdgcn_mfma_f32_16x16x32_bf16(af[i], bf[j], acc[i][j], 0, 0, 0);
  }

#pragma unroll
  for (int j = 0; j < 4; ++j) {
    const int col = n0 + wn + j * 16 + r;
    const float bv = bias[col];
#pragma unroll
    for (int i = 0; i < 4; ++i) {
#pragma unroll
      for (int rr = 0; rr < 4; ++rr) {
        const int row = m0 + wm + i * 16 + q * 4 + rr;
        const size_t idx = (size_t)row * N + col;
        float v = acc[i][j][rr] + bv;
        if constexpr (EPI == 0) {
          ((short*)Cv)[idx] = f2b(v);
        } else if constexpr (EPI == 1) {
          ((short*)Cv)[idx] = f2b(gelu_f(v));
        } else if constexpr (EPI == 2) {
          ((float*)Cv)[idx] = v;
        } else if constexpr (EPI == 3) {
          ((float*)Cv)[idx] = sigmoid_f(v + ((const float*)aux0)[idx]);
        } else if constexpr (EPI == 4) {
          ((float*)Cv)[idx] = v + ((const float*)aux0)[idx] + b2f(((const short*)aux1)[idx]);
        } else {
          ((float*)Cv)[idx] = v + ((const float*)aux0)[idx];
        }
      }
    }
  }
}

// ---------------------------------------------------------------------------
// fp32 -> bf16 transpose: out[C][R] = bf16(in[R][C]).  64x64 tiles, (16,16).
// ---------------------------------------------------------------------------
__global__ __launch_bounds__(256) void transpose_k(const float* __restrict__ in,
                                                   short* __restrict__ out,
                                                   int R, int C) {
  __shared__ float t[64][68];
  const int tx = threadIdx.x, ty = threadIdx.y;
  const int c0 = blockIdx.x * 64, r0 = blockIdx.y * 64;
#pragma unroll
  for (int yy = 0; yy < 64; yy += 16) {
    const float4 v = *(const float4*)&in[(size_t)(r0 + ty + yy) * C + c0 + tx * 4];
    t[ty + yy][tx * 4 + 0] = v.x;
    t[ty + yy][tx * 4 + 1] = v.y;
    t[ty + yy][tx * 4 + 2] = v.z;
    t[ty + yy][tx * 4 + 3] = v.w;
  }
  __syncthreads();
#pragma unroll
  for (int yy = 0; yy < 64; yy += 16) {
    short4 v;
    v.x = f2b(t[tx * 4 + 0][ty + yy]);
    v.y = f2b(t[tx * 4 + 1][ty + yy]);
    v.z = f2b(t[tx * 4 + 2][ty + yy]);
    v.w = f2b(t[tx * 4 + 3][ty + yy]);
    *(short4*)&out[(size_t)(c0 + ty + yy) * R + r0 + tx * 4] = v;
  }
}

// ---------------------------------------------------------------------------
// fp32 -> bf16 convert (4 elems/thread)
// ---------------------------------------------------------------------------
__global__ __launch_bounds__(256) void cvt_k(const float* __restrict__ in,
                                             short* __restrict__ out) {
  const size_t i = ((size_t)blockIdx.x * 256 + threadIdx.x) * 4;
  const float4 v = *(const float4*)(in + i);
  short4 o;
  o.x = f2b(v.x); o.y = f2b(v.y); o.z = f2b(v.z); o.w = f2b(v.w);
  *(short4*)(out + i) = o;
}

// ---------------------------------------------------------------------------
// RMSNorm row kernel (D=2048), fp32 in, fp32 weight, bf16 out.
// out = w * x / (sqrt(mean(x^2)) + eps)
// ---------------------------------------------------------------------------
__global__ __launch_bounds__(256) void rmsnorm_k(const float* __restrict__ in,
                                                 const float* __restrict__ w,
                                                 short* __restrict__ out) {
  const int row = blockIdx.x;
  const int tid = threadIdx.x;
  const size_t base = (size_t)row * 2048;
  float v[8];
  const float* p = in + base + tid * 8;
#pragma unroll
  for (int i = 0; i < 8; ++i) v[i] = p[i];
  float ss = 0.f;
#pragma unroll
  for (int i = 0; i < 8; ++i) ss += v[i] * v[i];
  for (int off = 32; off; off >>= 1) ss += __shfl_down(ss, off);
  __shared__ float red[4];
  __shared__ float sscale;
  if ((tid & 63) == 0) red[tid >> 6] = ss;
  __syncthreads();
  if (tid == 0) {
    float tot = red[0] + red[1] + red[2] + red[3];
    sscale = 1.f / (sqrtf(tot * (1.f / 2048.f)) + 1e-6f);
  }
  __syncthreads();
  const float scale = sscale;
  short* o = out + base + tid * 8;
#pragma unroll
  for (int i = 0; i < 8; ++i) o[i] = f2b(w[tid * 8 + i] * v[i] * scale);
}

// ---------------------------------------------------------------------------
// h_t = z * sigmoid(gpre) + gamma * x   (z,gpre bf16; gamma,x fp32; ht bf16)
// ---------------------------------------------------------------------------
__global__ __launch_bounds__(256) void ht_k(const short* __restrict__ z,
                                            const short* __restrict__ gp,
                                            const float* __restrict__ gamma,
                                            const float* __restrict__ x,
                                            short* __restrict__ ht) {
  const size_t i = ((size_t)blockIdx.x * 256 + threadIdx.x) * 4;
  const short4 z4 = *(const short4*)(z + i);
  const short4 g4 = *(const short4*)(gp + i);
  const float4 x4 = *(const float4*)(x + i);
  const float4 gm = *(const float4*)(gamma + i);
  short4 o;
  o.x = f2b(b2f(z4.x) * sigmoid_f(b2f(g4.x)) + gm.x * x4.x);
  o.y = f2b(b2f(z4.y) * sigmoid_f(b2f(g4.y)) + gm.y * x4.y);
  o.z = f2b(b2f(z4.z) * sigmoid_f(b2f(g4.z)) + gm.z * x4.z);
  o.w = f2b(b2f(z4.w) * sigmoid_f(b2f(g4.w)) + gm.w * x4.w);
  *(short4*)(ht + i) = o;
}

// ---------------------------------------------------------------------------
// cumprod over the reshaped (B,H,S,dh) view, axis=2.
// Within batch: flat = h*2^18 + s2*2^7 + e ; chain over s2 (0..2047).
// ---------------------------------------------------------------------------
__global__ __launch_bounds__(128) void cumprod1_k(float* __restrict__ gamma,
                                                  float* __restrict__ segprod) {
  const int bx = blockIdx.x;           // b*128 + h*8 + seg
  const int b = bx >> 7, h = (bx >> 3) & 15, seg = bx & 7;
  size_t base = (size_t)b * 4194304 + (size_t)h * 262144 + (size_t)seg * 256 * 128 + threadIdx.x;
  float acc = 1.f;
  for (int s = 0; s < 256; ++s) {
    acc *= gamma[base + (size_t)s * 128];
    gamma[base + (size_t)s * 128] = acc;
  }
  segprod[(size_t)bx * 128 + threadIdx.x] = acc;
}

__global__ __launch_bounds__(128) void cumprod2_k(const float* __restrict__ gamma,
                                                  const float* __restrict__ segprod,
                                                  float* __restrict__ out) {
  const int bx = blockIdx.x;
  const int b = bx >> 7, h = (bx >> 3) & 15, seg = bx & 7;
  size_t base = (size_t)b * 4194304 + (size_t)h * 262144 + (size_t)seg * 256 * 128 + threadIdx.x;
  float pre = 1.f;
  const size_t sp0 = (size_t)(bx & ~7) * 128 + threadIdx.x;
  for (int t = 0; t < seg; ++t) pre *= segprod[sp0 + (size_t)t * 128];
  for (int s = 0; s < 256; ++s)
    out[base + (size_t)s * 128] = gamma[base + (size_t)s * 128] * pre;
}

// ---------------------------------------------------------------------------
// Memory attention: per (b,h), 32 query rows/block, M=64 mem tokens, dh=128.
// block = 512 threads = 32 groups of 16. All operands bf16, fp32 math.
// ---------------------------------------------------------------------------
__global__ __launch_bounds__(512) void attn_k(const short* __restrict__ qa,
                                              const short* __restrict__ ka,
                                              const short* __restrict__ va,
                                              short* __restrict__ ctx) {
  __shared__ short sk[64][136];
  __shared__ short sv[64][136];
  __shared__ float sq[32][128];
  __shared__ float ss[32][64];
  const int tid = threadIdx.x;
  const int b = blockIdx.z, h = blockIdx.y;
  const int s0 = blockIdx.x * 32;
  const size_t hoff = (size_t)h * 128;
  for (int i = tid; i < 64 * 128; i += 512) {
    int m = i >> 7, d = i & 127;
    sk[m][d] = ka[((size_t)b * 64 + m) * 2048 + hoff + d];
    sv[m][d] = va[((size_t)b * 64 + m) * 2048 + hoff + d];
  }
  for (int i = tid; i < 32 * 128; i += 512) {
    int s = i >> 7, d = i & 127;
    sq[s][d] = b2f(qa[((size_t)b * 2048 + s0 + s) * 2048 + hoff + d]);
  }
  __syncthreads();
  const int g = tid >> 4;  // query row within block
  const int t = tid & 15;
  float sc[4];
#pragma unroll
  for (int mi = 0; mi < 4; ++mi) {
    const int m = mi * 16 + t;
    float a = 0.f;
    for (int d = 0; d < 128; ++d) a += sq[g][d] * b2f(sk[m][d]);
    sc[mi] = a * 0.08838834764831843f;  // 1/sqrt(128)
  }
  float mx = fmaxf(fmaxf(sc[0], sc[1]), fmaxf(sc[2], sc[3]));
#pragma unroll
  for (int off = 8; off; off >>= 1) mx = fmaxf(mx, __shfl_xor(mx, off, 16));
  float sum = 0.f;
#pragma unroll
  for (int mi = 0; mi < 4; ++mi) { sc[mi] = __expf(sc[mi] - mx); sum += sc[mi]; }
#pragma unroll
  for (int off = 8; off; off >>= 1) sum += __shfl_xor(sum, off, 16);
  const float inv = 1.f / sum;
#pragma unroll
  for (int mi = 0; mi < 4; ++mi) ss[g][mi * 16 + t] = sc[mi] * inv;
  __syncthreads();
  const int d0 = t * 8;
  float o[8] = {};
  for (int m = 0; m < 64; ++m) {
    const float wgt = ss[g][m];
#pragma unroll
    for (int i = 0; i < 8; ++i) o[i] += wgt * b2f(sv[m][d0 + i]);
  }
  short* op = ctx + ((size_t)b * 2048 + s0 + g) * 2048 + hoff + d0;
#pragma unroll
  for (int i = 0; i < 8; ++i) op[i] = f2b(o[i]);
}

// ---------------------------------------------------------------------------
extern "C" void kernel_launch(void* const* d_in, const int* in_sizes, int n_in,
                              void* d_out, int out_size, void* d_ws, size_t ws_size,
                              hipStream_t stream) {
  (void)in_sizes; (void)n_in; (void)out_size; (void)ws_size;
  // inputs (setup_inputs dict order, all fp32); wq/bq and wv/bv are dead
  const float* x   = (const float*)d_in[0];
  const float* mem = (const float*)d_in[1];
  const float* wk  = (const float*)d_in[3];
  const float* wz  = (const float*)d_in[5];
  const float* wg  = (const float*)d_in[6];
  const float* md1 = (const float*)d_in[7];
  const float* md2 = (const float*)d_in[8];
  const float* mcw = (const float*)d_in[9];
  const float* awq = (const float*)d_in[10];
  const float* awk = (const float*)d_in[11];
  const float* awv = (const float*)d_in[12];
  const float* awo = (const float*)d_in[13];
  const float* f1  = (const float*)d_in[14];
  const float* f2  = (const float*)d_in[15];
  const float* bk  = (const float*)d_in[17];
  const float* bz  = (const float*)d_in[19];
  const float* bg  = (const float*)d_in[20];
  const float* mb1 = (const float*)d_in[21];
  const float* mb2 = (const float*)d_in[22];
  const float* mcb = (const float*)d_in[23];
  const float* abq = (const float*)d_in[24];
  const float* abk = (const float*)d_in[25];
  const float* abv = (const float*)d_in[26];
  const float* abo = (const float*)d_in[27];
  const float* fb1 = (const float*)d_in[28];
  const float* fb2 = (const float*)d_in[29];
  const float* n1w = (const float*)d_in[30];
  const float* n2w = (const float*)d_in[31];

  // workspace layout (bytes); total ~296 MB
  char* W = (char*)d_ws;
  short* wkT  = (short*)(W + 0);
  short* wzT  = (short*)(W + 8388608);
  short* wgT  = (short*)(W + 16777216);
  short* mcwT = (short*)(W + 25165824);
  short* md1T = (short*)(W + 33554432);
  short* md2T = (short*)(W + 35651584);
  short* awqT = (short*)(W + 37748736);
  short* awkT = (short*)(W + 46137344);
  short* awvT = (short*)(W + 54525952);
  short* awoT = (short*)(W + 62914560);
  short* f1T  = (short*)(W + 71303168);
  short* f2T  = (short*)(W + 104857600);
  char*  big  = W + 138412032;               // 64 MB region, reused as t2
  short* xn   = (short*)(big + 0);
  short* kk   = (short*)(big + 16777216);    // later: ctx
  short* z    = (short*)(big + 33554432);
  short* gpre = (short*)(big + 50331648);
  short* ctx  = kk;
  short* t2   = (short*)big;
  short* t1   = (short*)(W + 205520896);
  float* gamma = (float*)(W + 209715200);    // later: xres (fp32)
  float* xres  = gamma;
  short* ht   = (short*)(W + 243269632);
  short* qa   = (short*)(W + 260046848);
  short* xn2  = qa;
  short* xb   = (short*)(W + 276824064);
  short* memb = (short*)(W + 293601280);
  short* ka   = (short*)(W + 294125568);
  short* va   = (short*)(W + 294649856);
  float* segprod = (float*)(W + 295174144);

  float* out0 = (float*)d_out;               // output  (B,S,D) fp32
  float* out1 = out0 + 8388608;              // cumprod (B,S,D) fp32

  const dim3 tb16(16, 16);
  // 1) weight transposes (fp32 -> bf16, Bt layout [N][K])
  transpose_k<<<dim3(32, 32), tb16, 0, stream>>>(wk, wkT, 2048, 2048);
  transpose_k<<<dim3(32, 32), tb16, 0, stream>>>(wz, wzT, 2048, 2048);
  transpose_k<<<dim3(32, 32), tb16, 0, stream>>>(wg, wgT, 2048, 2048);
  transpose_k<<<dim3(32, 32), tb16, 0, stream>>>(mcw, mcwT, 2048, 2048);
  transpose_k<<<dim3(8, 32), tb16, 0, stream>>>(md1, md1T, 2048, 512);
  transpose_k<<<dim3(32, 8), tb16, 0, stream>>>(md2, md2T, 512, 2048);
  transpose_k<<<dim3(32, 32), tb16, 0, stream>>>(awq, awqT, 2048, 2048);
  transpose_k<<<dim3(32, 32), tb16, 0, stream>>>(awk, awkT, 2048, 2048);
  transpose_k<<<dim3(32, 32), tb16, 0, stream>>>(awv, awvT, 2048, 2048);
  transpose_k<<<dim3(32, 32), tb16, 0, stream>>>(awo, awoT, 2048, 2048);
  transpose_k<<<dim3(128, 32), tb16, 0, stream>>>(f1, f1T, 2048, 8192);
  transpose_k<<<dim3(32, 128), tb16, 0, stream>>>(f2, f2T, 8192, 2048);

  // 2) converts + first norm
  cvt_k<<<8192, 256, 0, stream>>>(x, xb);
  cvt_k<<<256, 256, 0, stream>>>(mem, memb);
  rmsnorm_k<<<4096, 256, 0, stream>>>(x, n1w, xn);

  // 3-5) projections
  gemm_k<0><<<dim3(16, 32), 256, 0, stream>>>(xn, wkT, bk, kk, nullptr, nullptr, 4096, 2048, 2048);
  gemm_k<0><<<dim3(16, 32), 256, 0, stream>>>(xn, wzT, bz, z, nullptr, nullptr, 4096, 2048, 2048);
  gemm_k<0><<<dim3(16, 32), 256, 0, stream>>>(xb, wgT, bg, gpre, nullptr, nullptr, 4096, 2048, 2048);

  // 6-8) gamma = sigmoid(gelu(z@md1+mb1)@md2 + mb2 + k_@mcw + mcb)
  gemm_k<1><<<dim3(4, 32), 256, 0, stream>>>(z, md1T, mb1, t1, nullptr, nullptr, 4096, 512, 2048);
  gemm_k<2><<<dim3(16, 32), 256, 0, stream>>>(t1, md2T, mb2, gamma, nullptr, nullptr, 4096, 2048, 512);
  gemm_k<3><<<dim3(16, 32), 256, 0, stream>>>(kk, mcwT, mcb, gamma, gamma, nullptr, 4096, 2048, 2048);

  // 9) h_t = z*sigmoid(gpre) + gamma*x   (before cumprod destroys gamma)
  ht_k<<<8192, 256, 0, stream>>>(z, gpre, gamma, x, ht);

  // 10-11) cumprod -> out1 (fp32)
  cumprod1_k<<<256, 128, 0, stream>>>(gamma, segprod);
  cumprod2_k<<<256, 128, 0, stream>>>(gamma, segprod, out1);

  // 12-14) attention projections
  gemm_k<0><<<dim3(16, 32), 256, 0, stream>>>(ht, awqT, abq, qa, nullptr, nullptr, 4096, 2048, 2048);
  gemm_k<0><<<dim3(16, 1), 256, 0, stream>>>(memb, awkT, abk, ka, nullptr, nullptr, 128, 2048, 2048);
  gemm_k<0><<<dim3(16, 1), 256, 0, stream>>>(memb, awvT, abv, va, nullptr, nullptr, 128, 2048, 2048);

  // 15) attention -> ctx
  attn_k<<<dim3(64, 16, 2), 512, 0, stream>>>(qa, ka, va, ctx);

  // 16) xres = ctx@awo + abo + x + ht   (fp32)
  gemm_k<4><<<dim3(16, 32), 256, 0, stream>>>(ctx, awoT, abo, xres, x, ht, 4096, 2048, 2048);

  // 17) xn2 = rmsnorm(xres, n2w)
  rmsnorm_k<<<4096, 256, 0, stream>>>(xres, n2w, xn2);

  // 18-19) FFN: out0 = xres + gelu(xn2@f1+fb1)@f2 + fb2
  gemm_k<1><<<dim3(64, 32), 256, 0, stream>>>(xn2, f1T, fb1, t2, nullptr, nullptr, 4096, 8192, 2048);
  gemm_k<5><<<dim3(16, 32), 256, 0, stream>>>(t2, f2T, fb2, out0, xres, nullptr, 4096, 2048, 8192);
}